// Round 10
// baseline (608.694 us; speedup 1.0000x reference)
//
#include <hip/hip_runtime.h>
#include <hip/hip_cooperative_groups.h>
#include <math.h>

namespace cg = cooperative_groups;

// BlockwiseEarlyExitMamba: B=128, L=64, EXIT_POS=32 -> only t<32 matter.
// v11: cooperative 256-block kernel. Each batch is split across 2 blocks by
// channel half (h = bid>>7, b = bid&127; partner bid+-128 lands on the SAME
// XCD under round-robin dispatch -> L2-local exchange). Per block: half the
// GEMM weight loads, scan n-states split across thread pairs (shfl_xor(1)).
// Cross-block: xproj partial (2KB) and outproj partial (32KB) via workspace
// + grid.sync() (2 per layer). All 256 CUs active.
#define BATCH 128

using bf16x8 = __attribute__((ext_vector_type(8))) short;
using f32x4  = __attribute__((ext_vector_type(4))) float;
typedef unsigned short ushort_t;
typedef unsigned int   uint_t;

__device__ __forceinline__ float silu_f(float x) { return x / (1.f + __expf(-x)); }

__device__ __forceinline__ ushort_t bf16_rne(float f) {
  unsigned int u = __float_as_uint(f);
  u += 0x7FFFu + ((u >> 16) & 1u);
  return (ushort_t)(u >> 16);
}
__device__ __forceinline__ float bf16_to_f(ushort_t h) {
  return __uint_as_float(((unsigned int)h) << 16);
}
__device__ __forceinline__ void bf16_split(float f, ushort_t& hi, ushort_t& lo) {
  hi = bf16_rne(f);
  lo = bf16_rne(f - bf16_to_f(hi));
}

// split-bf16 3-MFMA: (ah+al)*(wh+wl) ~= ah*wh + ah*wl + al*wh
__device__ __forceinline__ f32x4 mfma3(bf16x8 ah, bf16x8 al, bf16x8 wh, bf16x8 wl, f32x4 acc) {
  acc = __builtin_amdgcn_mfma_f32_16x16x32_bf16(ah, wh, acc, 0, 0, 0);
  acc = __builtin_amdgcn_mfma_f32_16x16x32_bf16(ah, wl, acc, 0, 0, 0);
  acc = __builtin_amdgcn_mfma_f32_16x16x32_bf16(al, wh, acc, 0, 0, 0);
  return acc;
}

// ---------------- merged weight prep: fp32 -> hi/lo bf16 ----------------
#define NIP (4*1024*256)     // in_proj
#define NOP (4*256*512)      // out_proj
#define NXP (4*64*512)       // xproj padded 48->64 rows
#define NFW (256*160)        // fusion_w padded 136->160 cols
#define NPREP (NIP+NOP+NXP+NFW)   // 1744896 = 6816*256
__global__ __launch_bounds__(256) void prep_w(
    const float* __restrict__ ipw, const float* __restrict__ opw,
    const float* __restrict__ xpw, const float* __restrict__ fw,
    ushort_t* __restrict__ ih, ushort_t* __restrict__ il,
    ushort_t* __restrict__ oh, ushort_t* __restrict__ ol,
    ushort_t* __restrict__ xh, ushort_t* __restrict__ xl,
    ushort_t* __restrict__ fh, ushort_t* __restrict__ fl) {
  int i = blockIdx.x*256 + threadIdx.x;
  float v; ushort_t h, l;
  if (i < NIP) {
    v = ipw[i]; bf16_split(v, h, l); ih[i] = h; il[i] = l;
  } else if (i < NIP+NOP) {
    int j = i - NIP;
    v = opw[j]; bf16_split(v, h, l); oh[j] = h; ol[j] = l;
  } else if (i < NIP+NOP+NXP) {
    int j = i - (NIP+NOP);
    int lay = j >> 15;            // 64*512 = 32768
    int r = (j >> 9) & 63, c = j & 511;
    v = (r < 48) ? xpw[(size_t)lay*48*512 + r*512 + c] : 0.f;
    bf16_split(v, h, l); xh[j] = h; xl[j] = l;
  } else {
    int j = i - (NIP+NOP+NXP);
    int r = j / 160, c = j - r*160;
    v = (c < 136) ? fw[r*136 + c] : 0.f;
    bf16_split(v, h, l); fh[j] = h; fl[j] = l;
  }
}

// ---------------- LDS layout (bytes) ----------------
// A: sF32 f32 [32][260]                  33280  (full feat, persistent)
// B: sFh/sFl us [32][264] x2             33792  (feat hi/lo; aliased sT2 f32 [32][260])
// C: sUh/sUl us [32][264] x2             33792  (own-half u -> y; aliased catH/catL)
// D: sDbc f32 [32][68]                    8704  (dbc; aliased sHid f32[128])
#define OFF_A 0
#define OFF_B 33280
#define OFF_C 67072
#define OFF_D 100864
#define SMEM_TOTAL 109568

// LN of a [32][256] tile in LDS; 16 threads/row. Reads sIn (+resid +addv),
// internal barrier, writes sF32o + hi/lo bf16.
__device__ __forceinline__ void ln_block(
    const float* sIn, const float* resid, const float* addv,
    const float* __restrict__ g, const float* __restrict__ bb,
    float* sF32o, ushort_t* sFho, ushort_t* sFlo, int tid) {
  int row = tid >> 4, sub = tid & 15;
  float v[16];
  float s = 0.f;
  #pragma unroll
  for (int i = 0; i < 16; ++i) {
    int c = sub + 16*i;
    float t = sIn[row*260 + c];
    if (resid) t += resid[row*260 + c];
    if (addv)  t += addv[c];
    v[i] = t; s += t;
  }
  s += __shfl_xor(s, 1); s += __shfl_xor(s, 2); s += __shfl_xor(s, 4); s += __shfl_xor(s, 8);
  float mu = s * (1.f/256.f);
  float s2 = 0.f;
  #pragma unroll
  for (int i = 0; i < 16; ++i) { float dv = v[i]-mu; s2 += dv*dv; }
  s2 += __shfl_xor(s2, 1); s2 += __shfl_xor(s2, 2); s2 += __shfl_xor(s2, 4); s2 += __shfl_xor(s2, 8);
  float rs = rsqrtf(s2*(1.f/256.f) + 1e-5f);
  __syncthreads();              // sIn aliases sFho/sFlo: read-before, write-after
  #pragma unroll
  for (int i = 0; i < 16; ++i) {
    int c = sub + 16*i;
    float o = (v[i]-mu)*rs*g[c] + bb[c];
    sF32o[row*260 + c] = o;
    ushort_t hh, ll; bf16_split(o, hh, ll);
    sFho[row*264 + c] = hh;
    sFlo[row*264 + c] = ll;
  }
}

struct KParams {
  const float *x, *ep, *ef, *ed, *plw, *plb, *piw, *pib;
  const ushort_t *fw_h, *fw_l;
  const float *fb, *tng, *tnb;
  const ushort_t *ipw_h, *ipw_l;
  const float *cw, *cb;
  const ushort_t *xpw_h, *xpw_l;
  const float *dpw, *dpb, *alog, *dsk;
  const ushort_t *opw_h, *opw_l;
  const float *lng, *lnb, *w1, *b1, *w2, *b2;
  float *gdbc;   // [256][32*64] xproj partials
  float *gop;    // [256][32*256] outproj partials
  float *out;
};

// ---------------- cooperative mega kernel ----------------
__global__ __launch_bounds__(512, 2) void mega_kernel(KParams P) {
  cg::grid_group grid = cg::this_grid();
  extern __shared__ __align__(16) char sm[];
  float*    sF32 = (float*)(sm + OFF_A);       // [32][260]
  ushort_t* sFh  = (ushort_t*)(sm + OFF_B);    // [32][264]
  ushort_t* sFl  = sFh + 32*264;
  float*    sT2  = (float*)(sm + OFF_B);       // [32][260] (tokenizer pre / outproj sum)
  ushort_t* sUh  = (ushort_t*)(sm + OFF_C);    // [32][264] own-half u -> y
  ushort_t* sUl  = sUh + 32*264;
  ushort_t* catH = (ushort_t*)(sm + OFF_C);    // [32][168] (tokenizer only)
  ushort_t* catL = catH + 32*168;
  float*    sDbc = (float*)(sm + OFF_D);       // [32][68]
  float*    sHid = (float*)(sm + OFF_D);       // [128] (classifier only)

  const int tid  = threadIdx.x;
  const int bid  = blockIdx.x;
  const int b    = bid & 127;                  // batch
  const int h    = bid >> 7;                   // channel half (partner = same XCD)
  const int wave = tid >> 6, lane = tid & 63;
  const int lm   = lane & 15, lq = lane >> 4;

  // ================= tokenizer (duplicated per pair; deterministic) =========
  {
    int r = tid >> 4, cl = tid & 15;
    const float* xr = P.x + ((size_t)b*64 + r)*5;   // L=64 stride in input
    float x0 = xr[0], x1 = xr[1], x2 = xr[2], x3 = xr[3], x4 = xr[4];
    int proto = min(max((int)x0, 0), 255);
    int flags = min(max((int)x2, 0), 63);
    int direc = min(max((int)x4, 0), 1);
    #pragma unroll
    for (int j = 0; j < 10; ++j) {
      int c = cl + 16*j;
      float v;
      if (c < 32)       v = P.ep[proto*32 + c];
      else if (c < 64)  v = x1*P.plw[c-32] + P.plb[c-32];
      else if (c < 96)  v = P.ef[flags*32 + (c-64)];
      else if (c < 128) v = x3*P.piw[c-96] + P.pib[c-96];
      else if (c < 136) v = P.ed[direc*8 + (c-128)];
      else              v = 0.f;
      ushort_t hh, ll; bf16_split(v, hh, ll);
      catH[r*168 + c] = hh;
      catL[r*168 + c] = ll;
    }
  }
  __syncthreads();
  // fusion GEMM: pre = cat @ fw^T (M=32, N=256, K=160); 8 waves x 32 cols
  {
    f32x4 acc[2][2];
    #pragma unroll
    for (int mi = 0; mi < 2; ++mi)
      #pragma unroll
      for (int nt = 0; nt < 2; ++nt) acc[mi][nt] = (f32x4){0.f,0.f,0.f,0.f};
    int nb = wave*32;
    for (int k0 = 0; k0 < 160; k0 += 32) {
      bf16x8 fAh[2], fAl[2];
      #pragma unroll
      for (int mi = 0; mi < 2; ++mi) {
        int rr = mi*16 + lm;
        fAh[mi] = *(const bf16x8*)(catH + rr*168 + k0 + lq*8);
        fAl[mi] = *(const bf16x8*)(catL + rr*168 + k0 + lq*8);
      }
      #pragma unroll
      for (int nt = 0; nt < 2; ++nt) {
        int row = nb + nt*16 + lm;
        bf16x8 wh = *(const bf16x8*)(P.fw_h + (size_t)row*160 + k0 + lq*8);
        bf16x8 wl = *(const bf16x8*)(P.fw_l + (size_t)row*160 + k0 + lq*8);
        #pragma unroll
        for (int mi = 0; mi < 2; ++mi) acc[mi][nt] = mfma3(fAh[mi], fAl[mi], wh, wl, acc[mi][nt]);
      }
    }
    __syncthreads();   // cat reads done; sT2 aliases C? no, sT2 is B; but keep order safe
    #pragma unroll
    for (int mi = 0; mi < 2; ++mi)
      #pragma unroll
      for (int nt = 0; nt < 2; ++nt)
        #pragma unroll
        for (int r2 = 0; r2 < 4; ++r2)
          sT2[(mi*16 + lq*4 + r2)*260 + nb + nt*16 + lm] = acc[mi][nt][r2];
  }
  __syncthreads();
  ln_block(sT2, nullptr, P.fb, P.tng, P.tnb, sF32, sFh, sFl, tid);
  __syncthreads();

  // ================= 4 mamba layers =================
  #pragma unroll 1
  for (int l = 0; l < 4; ++l) {
    const ushort_t* iph = P.ipw_h + (size_t)l*1024*256;
    const ushort_t* ipl2= P.ipw_l + (size_t)l*1024*256;
    const ushort_t* xph = P.xpw_h + (size_t)l*64*512;
    const ushort_t* xpl = P.xpw_l + (size_t)l*64*512;
    const ushort_t* oph = P.opw_h + (size_t)l*256*512;
    const ushort_t* opl = P.opw_l + (size_t)l*256*512;

    // ---- U GEMM: own-half u_pre (N=256), 8 waves x 32 cols -> bf16 LDS ----
    {
      f32x4 acc[2][2];
      #pragma unroll
      for (int mi = 0; mi < 2; ++mi)
        #pragma unroll
        for (int nt = 0; nt < 2; ++nt) acc[mi][nt] = (f32x4){0.f,0.f,0.f,0.f};
      int rowbase = h*256 + wave*32;
      for (int k0 = 0; k0 < 256; k0 += 32) {
        bf16x8 fAh[2], fAl[2];
        #pragma unroll
        for (int mi = 0; mi < 2; ++mi) {
          int rr = mi*16 + lm;
          fAh[mi] = *(const bf16x8*)(sFh + rr*264 + k0 + lq*8);
          fAl[mi] = *(const bf16x8*)(sFl + rr*264 + k0 + lq*8);
        }
        #pragma unroll
        for (int nt = 0; nt < 2; ++nt) {
          int row = rowbase + nt*16 + lm;
          bf16x8 wh = *(const bf16x8*)(iph + (size_t)row*256 + k0 + lq*8);
          bf16x8 wl = *(const bf16x8*)(ipl2 + (size_t)row*256 + k0 + lq*8);
          #pragma unroll
          for (int mi = 0; mi < 2; ++mi) acc[mi][nt] = mfma3(fAh[mi], fAl[mi], wh, wl, acc[mi][nt]);
        }
      }
      int nb = wave*32;
      #pragma unroll
      for (int mi = 0; mi < 2; ++mi)
        #pragma unroll
        for (int nt = 0; nt < 2; ++nt)
          #pragma unroll
          for (int r2 = 0; r2 < 4; ++r2) {
            int t = mi*16 + lq*4 + r2;
            int n = nb + nt*16 + lm;
            ushort_t hh, ll; bf16_split(acc[mi][nt][r2], hh, ll);
            sUh[t*264 + n] = hh;
            sUl[t*264 + n] = ll;
          }
    }
    __syncthreads();

    // ---- conv + silu: c = tid&255 (local channel), hv = tid>>8 (t-half) ----
    {
      int c = tid & 255, hv = tid >> 8;
      int dg = h*256 + c;
      float xw[19];
      int h16 = hv*16;
      #pragma unroll
      for (int j = 0; j < 19; ++j) {
        int gt = h16 + j - 3;
        xw[j] = (gt >= 0) ? (bf16_to_f(sUh[gt*264 + c]) + bf16_to_f(sUl[gt*264 + c])) : 0.f;
      }
      __syncthreads();    // all reads done before in-place overwrite
      const float* cwl = P.cw + (size_t)l*2048 + (size_t)dg*4;
      float w0 = cwl[0], w1c = cwl[1], w2c = cwl[2], w3 = cwl[3];
      float bias = P.cb[l*512 + dg];
      #pragma unroll
      for (int tt = 0; tt < 16; ++tt) {
        float a = bias + w0*xw[tt] + w1c*xw[tt+1] + w2c*xw[tt+2] + w3*xw[tt+3];
        float uv = silu_f(a);
        ushort_t hh, ll; bf16_split(uv, hh, ll);
        sUh[(h16+tt)*264 + c] = hh;
        sUl[(h16+tt)*264 + c] = ll;
      }
    }
    __syncthreads();

    // ---- xproj partial: K = own 256; 4 row-groups x 2 K-halves ----
    {
      int wg = wave & 3, kh = wave >> 2;
      f32x4 acx[2] = {(f32x4){0.f,0.f,0.f,0.f}, (f32x4){0.f,0.f,0.f,0.f}};
      for (int k0 = 0; k0 < 128; k0 += 32) {
        bf16x8 fAh[2], fAl[2];
        #pragma unroll
        for (int mi = 0; mi < 2; ++mi) {
          int rr = mi*16 + lm;
          fAh[mi] = *(const bf16x8*)(sUh + rr*264 + kh*128 + k0 + lq*8);
          fAl[mi] = *(const bf16x8*)(sUl + rr*264 + kh*128 + k0 + lq*8);
        }
        int row = wg*16 + lm;
        bf16x8 wh = *(const bf16x8*)(xph + (size_t)row*512 + h*256 + kh*128 + k0 + lq*8);
        bf16x8 wl = *(const bf16x8*)(xpl + (size_t)row*512 + h*256 + kh*128 + k0 + lq*8);
        #pragma unroll
        for (int mi = 0; mi < 2; ++mi) acx[mi] = mfma3(fAh[mi], fAl[mi], wh, wl, acx[mi]);
      }
      if (kh == 1) {
        #pragma unroll
        for (int mi = 0; mi < 2; ++mi)
          #pragma unroll
          for (int r2 = 0; r2 < 4; ++r2)
            sDbc[(mi*16 + lq*4 + r2)*68 + wg*16 + lm] = acx[mi][r2];
      }
      __syncthreads();
      if (kh == 0) {
        #pragma unroll
        for (int mi = 0; mi < 2; ++mi)
          #pragma unroll
          for (int r2 = 0; r2 < 4; ++r2)
            sDbc[(mi*16 + lq*4 + r2)*68 + wg*16 + lm] += acx[mi][r2];
      }
    }
    __syncthreads();
    // export own dbc partial [32][64] -> gdbc[bid]
    {
      int i0 = tid*4;
      int t = i0 >> 6, c0 = i0 & 63;
      float4 v = *(const float4*)(sDbc + t*68 + c0);
      *(float4*)(P.gdbc + (size_t)bid*2048 + i0) = v;
    }
    grid.sync();
    // import partner partial, add
    {
      int i0 = tid*4;
      int t = i0 >> 6, c0 = i0 & 63;
      float4 v = *(const float4*)(P.gdbc + (size_t)(bid ^ 128)*2048 + i0);
      sDbc[t*68 + c0]     += v.x;
      sDbc[t*68 + c0 + 1] += v.y;
      sDbc[t*68 + c0 + 2] += v.z;
      sDbc[t*68 + c0 + 3] += v.w;
    }
    __syncthreads();

    // ---- dtproj + scan: thread pair per channel, n split 8+8 ----
    {
      int c = tid >> 1, p = tid & 1;           // pair lanes (2c,2c+1) same wave
      int dg = h*256 + c;
      const float* dpwl = P.dpw + (size_t)l*8192 + (size_t)dg*16 + p*8;
      float wv[8];
      #pragma unroll
      for (int j = 0; j < 8; ++j) wv[j] = dpwl[j];
      const float* al2 = P.alog + (size_t)l*8192 + (size_t)dg*16 + p*8;
      float cc[8], hst[8];
      #pragma unroll
      for (int j = 0; j < 8; ++j) {
        cc[j] = -__expf(al2[j]) * 1.44269504f;
        hst[j] = 0.f;
      }
      float bias = P.dpb[l*512 + dg], dskv = P.dsk[l*512 + dg];
      #pragma unroll 2
      for (int t = 0; t < 32; ++t) {
        const float* rowp = sDbc + t*68;
        float raw = 0.f;
        #pragma unroll
        for (int j = 0; j < 8; ++j) raw += wv[j]*rowp[p*8 + j];
        raw += __shfl_xor(raw, 1);
        raw += bias;
        float dtv = (raw > 20.f) ? raw : __logf(1.f + __expf(raw));
        int ui = t*264 + c;
        float uv = bf16_to_f(sUh[ui]) + bf16_to_f(sUl[ui]);
        float du = dtv * uv;
        float yv = 0.f;
        #pragma unroll
        for (int j = 0; j < 8; ++j) {
          int n = p*8 + j;
          float en = exp2f(dtv * cc[j]);
          hst[j] = en*hst[j] + du*rowp[16 + n];
          yv += hst[j]*rowp[32 + n];
        }
        yv += __shfl_xor(yv, 1);
        if (p == 0) {
          float yraw = yv + uv*dskv;
          ushort_t hh, ll; bf16_split(yraw, hh, ll);
          sUh[ui] = hh;
          sUl[ui] = ll;
        }
      }
    }
    __syncthreads();

    // ---- Z GEMM (own half) + fragment-space gate ----
    {
      f32x4 zf[2][2];
      #pragma unroll
      for (int mi = 0; mi < 2; ++mi)
        #pragma unroll
        for (int nt = 0; nt < 2; ++nt) zf[mi][nt] = (f32x4){0.f,0.f,0.f,0.f};
      int rowbase = 512 + h*256 + wave*32;
      for (int k0 = 0; k0 < 256; k0 += 32) {
        bf16x8 fAh[2], fAl[2];
        #pragma unroll
        for (int mi = 0; mi < 2; ++mi) {
          int rr = mi*16 + lm;
          fAh[mi] = *(const bf16x8*)(sFh + rr*264 + k0 + lq*8);
          fAl[mi] = *(const bf16x8*)(sFl + rr*264 + k0 + lq*8);
        }
        #pragma unroll
        for (int nt = 0; nt < 2; ++nt) {
          int row = rowbase + nt*16 + lm;
          bf16x8 wh = *(const bf16x8*)(iph + (size_t)row*256 + k0 + lq*8);
          bf16x8 wl = *(const bf16x8*)(ipl2 + (size_t)row*256 + k0 + lq*8);
          #pragma unroll
          for (int mi = 0; mi < 2; ++mi) zf[mi][nt] = mfma3(fAh[mi], fAl[mi], wh, wl, zf[mi][nt]);
        }
      }
      int nb = wave*32;
      #pragma unroll
      for (int mi = 0; mi < 2; ++mi)
        #pragma unroll
        for (int nt = 0; nt < 2; ++nt)
          #pragma unroll
          for (int r2 = 0; r2 < 4; ++r2) {
            int t  = mi*16 + lq*4 + r2;
            int lc = nb + nt*16 + lm;
            int idx = t*264 + lc;
            float yraw = bf16_to_f(sUh[idx]) + bf16_to_f(sUl[idx]);
            float g = yraw * silu_f(zf[mi][nt][r2]);
            ushort_t hh, ll; bf16_split(g, hh, ll);
            sUh[idx] = hh; sUl[idx] = ll;
          }
    }
    __syncthreads();

    // ---- outproj partial: K = own 256; 8 waves x 32 out cols ----
    {
      f32x4 ao[2][2];
      #pragma unroll
      for (int mi = 0; mi < 2; ++mi)
        #pragma unroll
        for (int nt = 0; nt < 2; ++nt) ao[mi][nt] = (f32x4){0.f,0.f,0.f,0.f};
      int nbo = wave*32;
      for (int k0 = 0; k0 < 256; k0 += 32) {
        bf16x8 yh[2], yl[2];
        #pragma unroll
        for (int mi = 0; mi < 2; ++mi) {
          int rr = mi*16 + lm;
          yh[mi] = *(const bf16x8*)(sUh + rr*264 + k0 + lq*8);
          yl[mi] = *(const bf16x8*)(sUl + rr*264 + k0 + lq*8);
        }
        #pragma unroll
        for (int nt = 0; nt < 2; ++nt) {
          int row = nbo + nt*16 + lm;
          bf16x8 wh = *(const bf16x8*)(oph + (size_t)row*512 + h*256 + k0 + lq*8);
          bf16x8 wl = *(const bf16x8*)(opl + (size_t)row*512 + h*256 + k0 + lq*8);
          #pragma unroll
          for (int mi = 0; mi < 2; ++mi) ao[mi][nt] = mfma3(yh[mi], yl[mi], wh, wl, ao[mi][nt]);
        }
      }
      __syncthreads();   // sFh reads (Z) done: sT2 (aliases sFh) now writable
      // dump own partial to sT2 AND export to gop[bid]
      #pragma unroll
      for (int mi = 0; mi < 2; ++mi)
        #pragma unroll
        for (int nt = 0; nt < 2; ++nt)
          #pragma unroll
          for (int r2 = 0; r2 < 4; ++r2) {
            int t = mi*16 + lq*4 + r2;
            int n = nbo + nt*16 + lm;
            sT2[t*260 + n] = ao[mi][nt][r2];
            P.gop[(size_t)bid*8192 + t*256 + n] = ao[mi][nt][r2];
          }
    }
    grid.sync();
    // import partner outproj partial, add into sT2
    {
      int t  = tid >> 4;
      int n0 = (tid & 15) * 16;
      const float* src = P.gop + (size_t)(bid ^ 128)*8192 + t*256 + n0;
      #pragma unroll
      for (int j4 = 0; j4 < 4; ++j4) {
        float4 v = *(const float4*)(src + j4*4);
        float* dst = sT2 + t*260 + n0 + j4*4;
        dst[0] += v.x; dst[1] += v.y; dst[2] += v.z; dst[3] += v.w;
      }
    }
    __syncthreads();
    ln_block(sT2, sF32, nullptr, P.lng, P.lnb, sF32, sFh, sFl, tid);
    __syncthreads();
  }

  // ================= classifier (token 31); only h==0 writes =================
  {
    int o = tid >> 2, q = tid & 3;
    const float* fr = sF32 + 31*260;
    const float* wr = P.w1 + (size_t)o*256 + q*64;
    float s = 0.f;
    #pragma unroll 16
    for (int k = 0; k < 64; ++k) s += wr[k]*fr[q*64 + k];
    s += __shfl_xor(s, 1); s += __shfl_xor(s, 2);
    if (q == 0) sHid[o] = fmaxf(s + P.b1[o], 0.f);
    __syncthreads();
    if (h == 0 && tid < 2) {
      float oo = P.b2[tid];
      #pragma unroll 8
      for (int k = 0; k < 128; ++k) oo += P.w2[tid*128 + k]*sHid[k];
      P.out[b*2 + tid] = oo;
    }
  }
}

// ---------------- launch ----------------
extern "C" void kernel_launch(void* const* d_in, const int* in_sizes, int n_in,
                              void* d_out, int out_size, void* d_ws, size_t ws_size,
                              hipStream_t stream) {
  const float* x    = (const float*)d_in[0];
  const float* ep   = (const float*)d_in[1];
  const float* ef   = (const float*)d_in[2];
  const float* ed   = (const float*)d_in[3];
  const float* plw  = (const float*)d_in[4];
  const float* plb  = (const float*)d_in[5];
  const float* piw  = (const float*)d_in[6];
  const float* pib  = (const float*)d_in[7];
  const float* fw   = (const float*)d_in[8];
  const float* fb   = (const float*)d_in[9];
  const float* tng  = (const float*)d_in[10];
  const float* tnb  = (const float*)d_in[11];
  const float* ipw  = (const float*)d_in[12];
  const float* cw   = (const float*)d_in[13];
  const float* cb   = (const float*)d_in[14];
  const float* xpw  = (const float*)d_in[15];
  const float* dpw  = (const float*)d_in[16];
  const float* dpb  = (const float*)d_in[17];
  const float* alog = (const float*)d_in[18];
  const float* dsk  = (const float*)d_in[19];
  const float* opw  = (const float*)d_in[20];
  const float* lng  = (const float*)d_in[21];
  const float* lnb  = (const float*)d_in[22];
  const float* w1   = (const float*)d_in[23];
  const float* b1   = (const float*)d_in[24];
  const float* w2   = (const float*)d_in[25];
  const float* b2   = (const float*)d_in[26];

  // workspace: split-bf16 weights + exchange buffers
  ushort_t* ipw_h = (ushort_t*)d_ws;
  ushort_t* ipw_l = ipw_h + (size_t)NIP;
  ushort_t* opw_h = ipw_l + (size_t)NIP;
  ushort_t* opw_l = opw_h + (size_t)NOP;
  ushort_t* xpw_h = opw_l + (size_t)NOP;
  ushort_t* xpw_l = xpw_h + (size_t)NXP;
  ushort_t* fw_h  = xpw_l + (size_t)NXP;
  ushort_t* fw_l  = fw_h  + (size_t)NFW;
  float*    gdbc  = (float*)(fw_l + (size_t)NFW);      // 256*2048 f32 = 2 MB
  float*    gop   = gdbc + (size_t)256*2048;           // 256*8192 f32 = 8 MB

  static int smem_set = 0;
  if (!smem_set) {
    hipFuncSetAttribute(reinterpret_cast<const void*>(mega_kernel),
                        hipFuncAttributeMaxDynamicSharedMemorySize, SMEM_TOTAL);
    smem_set = 1;
  }

  prep_w<<<NPREP/256, 256, 0, stream>>>(ipw, opw, xpw, fw,
      ipw_h, ipw_l, opw_h, opw_l, xpw_h, xpw_l, fw_h, fw_l);

  KParams P = { x, ep, ef, ed, plw, plb, piw, pib,
                fw_h, fw_l, fb, tng, tnb,
                ipw_h, ipw_l, cw, cb, xpw_h, xpw_l,
                dpw, dpb, alog, dsk, opw_h, opw_l,
                lng, lnb, w1, b1, w2, b2,
                gdbc, gop, (float*)d_out };
  void* args[] = { &P };
  hipLaunchCooperativeKernel(reinterpret_cast<const void*>(mega_kernel),
                             dim3(256), dim3(512), args, SMEM_TOTAL, stream);
}

// Round 11
// 455.680 us; speedup vs baseline: 1.3358x; 1.3358x over previous
//
#include <hip/hip_runtime.h>
#include <math.h>

// BlockwiseEarlyExitMamba: B=128, L=64, EXIT_POS=32 -> only t<32 matter.
// v12: v6 base (512-thread per-batch mega-kernel, 363us verified) with
// explicit 1-deep software prefetch (weights from global + A-frags from LDS)
// in all four GEMM k-loops. Z/U split into 2x32-col slices so the register
// peak stays < 128 (first slice's acc dumped before second slice runs).
// Everything else (phase order, barriers, conv/scan/LN) identical to v6.
#define BATCH 128

using bf16x8 = __attribute__((ext_vector_type(8))) short;
using f32x4  = __attribute__((ext_vector_type(4))) float;
typedef unsigned short ushort_t;
typedef unsigned int   uint_t;

__device__ __forceinline__ float silu_f(float x) { return x / (1.f + __expf(-x)); }

__device__ __forceinline__ ushort_t bf16_rne(float f) {
  unsigned int u = __float_as_uint(f);
  u += 0x7FFFu + ((u >> 16) & 1u);
  return (ushort_t)(u >> 16);
}
__device__ __forceinline__ float bf16_to_f(ushort_t h) {
  return __uint_as_float(((unsigned int)h) << 16);
}
__device__ __forceinline__ void bf16_split(float f, ushort_t& hi, ushort_t& lo) {
  hi = bf16_rne(f);
  lo = bf16_rne(f - bf16_to_f(hi));
}

// split-bf16 3-MFMA: (ah+al)*(wh+wl) ~= ah*wh + ah*wl + al*wh
__device__ __forceinline__ f32x4 mfma3(bf16x8 ah, bf16x8 al, bf16x8 wh, bf16x8 wl, f32x4 acc) {
  acc = __builtin_amdgcn_mfma_f32_16x16x32_bf16(ah, wh, acc, 0, 0, 0);
  acc = __builtin_amdgcn_mfma_f32_16x16x32_bf16(ah, wl, acc, 0, 0, 0);
  acc = __builtin_amdgcn_mfma_f32_16x16x32_bf16(al, wh, acc, 0, 0, 0);
  return acc;
}

// 2-tile (32 out cols) GEMM slice with 1-deep prefetch of A(LDS) + W(global).
// sAh/sAl pre-offset: + lm*AP + lq*8 (+ any K offset). wh/wl pre-offset:
// + (row0+lm)*WP + lq*8. Second row-tile at +16*AP / +16*WP.
template<int KSTEPS, int AP, int WP>
__device__ __forceinline__ void gemm2p(
    const ushort_t* sAh, const ushort_t* sAl,
    const ushort_t* wh, const ushort_t* wl,
    f32x4 acc[2][2]) {
  bf16x8 ca0  = *(const bf16x8*)(sAh);
  bf16x8 cal0 = *(const bf16x8*)(sAl);
  bf16x8 ca1  = *(const bf16x8*)(sAh + 16*AP);
  bf16x8 cal1 = *(const bf16x8*)(sAl + 16*AP);
  bf16x8 cw0  = *(const bf16x8*)(wh);
  bf16x8 cwl0 = *(const bf16x8*)(wl);
  bf16x8 cw1  = *(const bf16x8*)(wh + 16*WP);
  bf16x8 cwl1 = *(const bf16x8*)(wl + 16*WP);
  #pragma unroll
  for (int ks = 0; ks < KSTEPS; ++ks) {
    bf16x8 na0=ca0, nal0=cal0, na1=ca1, nal1=cal1;
    bf16x8 nw0=cw0, nwl0=cwl0, nw1=cw1, nwl1=cwl1;
    if (ks + 1 < KSTEPS) {
      int kn = (ks+1)*32;
      na0  = *(const bf16x8*)(sAh + kn);
      nal0 = *(const bf16x8*)(sAl + kn);
      na1  = *(const bf16x8*)(sAh + 16*AP + kn);
      nal1 = *(const bf16x8*)(sAl + 16*AP + kn);
      nw0  = *(const bf16x8*)(wh + kn);
      nwl0 = *(const bf16x8*)(wl + kn);
      nw1  = *(const bf16x8*)(wh + 16*WP + kn);
      nwl1 = *(const bf16x8*)(wl + 16*WP + kn);
    }
    acc[0][0] = mfma3(ca0, cal0, cw0, cwl0, acc[0][0]);
    acc[1][0] = mfma3(ca1, cal1, cw0, cwl0, acc[1][0]);
    acc[0][1] = mfma3(ca0, cal0, cw1, cwl1, acc[0][1]);
    acc[1][1] = mfma3(ca1, cal1, cw1, cwl1, acc[1][1]);
    ca0=na0; cal0=nal0; ca1=na1; cal1=nal1;
    cw0=nw0; cwl0=nwl0; cw1=nw1; cwl1=nwl1;
  }
}

// 1-tile (16 out cols) variant for xproj.
template<int KSTEPS, int AP, int WP>
__device__ __forceinline__ void gemm1p(
    const ushort_t* sAh, const ushort_t* sAl,
    const ushort_t* wh, const ushort_t* wl,
    f32x4 acc[2]) {
  bf16x8 ca0  = *(const bf16x8*)(sAh);
  bf16x8 cal0 = *(const bf16x8*)(sAl);
  bf16x8 ca1  = *(const bf16x8*)(sAh + 16*AP);
  bf16x8 cal1 = *(const bf16x8*)(sAl + 16*AP);
  bf16x8 cw0  = *(const bf16x8*)(wh);
  bf16x8 cwl0 = *(const bf16x8*)(wl);
  #pragma unroll
  for (int ks = 0; ks < KSTEPS; ++ks) {
    bf16x8 na0=ca0, nal0=cal0, na1=ca1, nal1=cal1;
    bf16x8 nw0=cw0, nwl0=cwl0;
    if (ks + 1 < KSTEPS) {
      int kn = (ks+1)*32;
      na0  = *(const bf16x8*)(sAh + kn);
      nal0 = *(const bf16x8*)(sAl + kn);
      na1  = *(const bf16x8*)(sAh + 16*AP + kn);
      nal1 = *(const bf16x8*)(sAl + 16*AP + kn);
      nw0  = *(const bf16x8*)(wh + kn);
      nwl0 = *(const bf16x8*)(wl + kn);
    }
    acc[0] = mfma3(ca0, cal0, cw0, cwl0, acc[0]);
    acc[1] = mfma3(ca1, cal1, cw0, cwl0, acc[1]);
    ca0=na0; cal0=nal0; ca1=na1; cal1=nal1;
    cw0=nw0; cwl0=nwl0;
  }
}

// ---------------- merged weight prep: fp32 -> hi/lo bf16 ----------------
#define NIP (4*1024*256)     // in_proj
#define NOP (4*256*512)      // out_proj
#define NXP (4*64*512)       // xproj padded 48->64 rows
#define NFW (256*160)        // fusion_w padded 136->160 cols
#define NPREP (NIP+NOP+NXP+NFW)   // 1744896 = 6816*256
__global__ __launch_bounds__(256) void prep_w(
    const float* __restrict__ ipw, const float* __restrict__ opw,
    const float* __restrict__ xpw, const float* __restrict__ fw,
    ushort_t* __restrict__ ih, ushort_t* __restrict__ il,
    ushort_t* __restrict__ oh, ushort_t* __restrict__ ol,
    ushort_t* __restrict__ xh, ushort_t* __restrict__ xl,
    ushort_t* __restrict__ fh, ushort_t* __restrict__ fl) {
  int i = blockIdx.x*256 + threadIdx.x;
  float v; ushort_t h, l;
  if (i < NIP) {
    v = ipw[i]; bf16_split(v, h, l); ih[i] = h; il[i] = l;
  } else if (i < NIP+NOP) {
    int j = i - NIP;
    v = opw[j]; bf16_split(v, h, l); oh[j] = h; ol[j] = l;
  } else if (i < NIP+NOP+NXP) {
    int j = i - (NIP+NOP);
    int lay = j >> 15;            // 64*512 = 32768
    int r = (j >> 9) & 63, c = j & 511;
    v = (r < 48) ? xpw[(size_t)lay*48*512 + r*512 + c] : 0.f;
    bf16_split(v, h, l); xh[j] = h; xl[j] = l;
  } else {
    int j = i - (NIP+NOP+NXP);
    int r = j / 160, c = j - r*160;
    v = (c < 136) ? fw[r*136 + c] : 0.f;
    bf16_split(v, h, l); fh[j] = h; fl[j] = l;
  }
}

// ---------------- LDS layout for mega kernel (bytes) ----------------
// A: sF32  f32 [32][260]                      33280   (residual feat, persistent)
// B: sFh/sFl us [32][264] x2                  33792   (feat hi/lo; aliased: sT2 f32 [32][260],
//                                                      sDbc f32 [32][68], sHid f32[128])
// C: sZT   f32 [32][524]                      67072   (staging; aliased: sUh/sUl us [32][520] x2,
//                                                      catH/catL us [32][168] x2; y overwrites u)
#define OFF_A 0
#define OFF_B 33280
#define OFF_C 67072
#define SMEM_TOTAL 134144

// LN of a [32][256] tile in LDS; 16 threads/row.
__device__ __forceinline__ void ln_block(
    const float* sIn, const float* resid, const float* addv,
    const float* __restrict__ g, const float* __restrict__ bb,
    float* sF32o, ushort_t* sFho, ushort_t* sFlo, int tid) {
  int row = tid >> 4, sub = tid & 15;
  float v[16];
  float s = 0.f;
  #pragma unroll
  for (int i = 0; i < 16; ++i) {
    int c = sub + 16*i;
    float t = sIn[row*260 + c];
    if (resid) t += resid[row*260 + c];
    if (addv)  t += addv[c];
    v[i] = t; s += t;
  }
  s += __shfl_xor(s, 1); s += __shfl_xor(s, 2); s += __shfl_xor(s, 4); s += __shfl_xor(s, 8);
  float mu = s * (1.f/256.f);
  float s2 = 0.f;
  #pragma unroll
  for (int i = 0; i < 16; ++i) { float dv = v[i]-mu; s2 += dv*dv; }
  s2 += __shfl_xor(s2, 1); s2 += __shfl_xor(s2, 2); s2 += __shfl_xor(s2, 4); s2 += __shfl_xor(s2, 8);
  float rs = rsqrtf(s2*(1.f/256.f) + 1e-5f);
  __syncthreads();              // sIn may alias sFho/sFlo: read-before, write-after
  #pragma unroll
  for (int i = 0; i < 16; ++i) {
    int c = sub + 16*i;
    float o = (v[i]-mu)*rs*g[c] + bb[c];
    sF32o[row*260 + c] = o;
    ushort_t hh, ll; bf16_split(o, hh, ll);
    sFho[row*264 + c] = hh;
    sFlo[row*264 + c] = ll;
  }
}

// ---------------- the mega kernel: tokenizer + 4 layers + classifier ----------
__global__ __launch_bounds__(512, 2) void mega_kernel(
    const float* __restrict__ x,
    const float* __restrict__ ep, const float* __restrict__ ef, const float* __restrict__ ed,
    const float* __restrict__ plw, const float* __restrict__ plb,
    const float* __restrict__ piw, const float* __restrict__ pib,
    const ushort_t* __restrict__ fw_h, const ushort_t* __restrict__ fw_l,
    const float* __restrict__ fb,
    const float* __restrict__ tng, const float* __restrict__ tnb,
    const ushort_t* __restrict__ ipw_h, const ushort_t* __restrict__ ipw_l,
    const float* __restrict__ cw, const float* __restrict__ cb,
    const ushort_t* __restrict__ xpw_h, const ushort_t* __restrict__ xpw_l,
    const float* __restrict__ dpw, const float* __restrict__ dpb,
    const float* __restrict__ alog, const float* __restrict__ dsk,
    const ushort_t* __restrict__ opw_h, const ushort_t* __restrict__ opw_l,
    const float* __restrict__ lng, const float* __restrict__ lnb,
    const float* __restrict__ w1, const float* __restrict__ b1,
    const float* __restrict__ w2, const float* __restrict__ b2,
    float* __restrict__ out) {
  extern __shared__ __align__(16) char sm[];
  float*    sF32 = (float*)(sm + OFF_A);       // [32][260]
  ushort_t* sFh  = (ushort_t*)(sm + OFF_B);    // [32][264]
  ushort_t* sFl  = sFh + 32*264;
  float*    sT2  = (float*)(sm + OFF_B);       // [32][260] GEMM frag dump
  float*    sDbc = (float*)(sm + OFF_B);       // [32][68]
  float*    sHid = (float*)(sm + OFF_B);       // [128]
  float*    sZT  = (float*)(sm + OFF_C);       // [32][524] f32 staging (z, then pre-conv u)
  ushort_t* sUh  = (ushort_t*)(sm + OFF_C);    // [32][520]  packed u hi -> later y hi
  ushort_t* sUl  = sUh + 32*520;               //            packed u lo -> later y lo
  ushort_t* catH = (ushort_t*)(sm + OFF_C);    // [32][168]
  ushort_t* catL = catH + 32*168;

  const int tid  = threadIdx.x;
  const int b    = blockIdx.x;
  const int wave = tid >> 6, lane = tid & 63;
  const int lm   = lane & 15, lq = lane >> 4;
  const int d    = tid;                        // channel owned by this thread (0..511)

  // ================= tokenizer =================
  {
    int r = tid >> 4, cl = tid & 15;
    const float* xr = x + ((size_t)b*64 + r)*5;   // L=64 stride in input
    float x0 = xr[0], x1 = xr[1], x2 = xr[2], x3 = xr[3], x4 = xr[4];
    int proto = min(max((int)x0, 0), 255);
    int flags = min(max((int)x2, 0), 63);
    int direc = min(max((int)x4, 0), 1);
    #pragma unroll
    for (int j = 0; j < 10; ++j) {
      int c = cl + 16*j;
      float v;
      if (c < 32)       v = ep[proto*32 + c];
      else if (c < 64)  v = x1*plw[c-32] + plb[c-32];
      else if (c < 96)  v = ef[flags*32 + (c-64)];
      else if (c < 128) v = x3*piw[c-96] + pib[c-96];
      else if (c < 136) v = ed[direc*8 + (c-128)];
      else              v = 0.f;
      ushort_t hh, ll; bf16_split(v, hh, ll);
      catH[r*168 + c] = hh;
      catL[r*168 + c] = ll;
    }
  }
  __syncthreads();
  // pre = cat @ fw^T (M=32, N=256, K=160); dump to sT2 (B region, free)
  {
    f32x4 acc[2][2];
    #pragma unroll
    for (int mi = 0; mi < 2; ++mi)
      #pragma unroll
      for (int nt = 0; nt < 2; ++nt) acc[mi][nt] = (f32x4){0.f,0.f,0.f,0.f};
    int nb = wave*32;
    gemm2p<5, 168, 160>(catH + lm*168 + lq*8, catL + lm*168 + lq*8,
                        fw_h + (size_t)(nb+lm)*160 + lq*8,
                        fw_l + (size_t)(nb+lm)*160 + lq*8, acc);
    #pragma unroll
    for (int mi = 0; mi < 2; ++mi)
      #pragma unroll
      for (int nt = 0; nt < 2; ++nt)
        #pragma unroll
        for (int r2 = 0; r2 < 4; ++r2)
          sT2[(mi*16 + lq*4 + r2)*260 + nb + nt*16 + lm] = acc[mi][nt][r2];
  }
  __syncthreads();
  ln_block(sT2, nullptr, fb, tng, tnb, sF32, sFh, sFl, tid);
  __syncthreads();

  // ================= 4 mamba layers =================
  #pragma unroll 1
  for (int l = 0; l < 4; ++l) {
    const ushort_t* iph = ipw_h + (size_t)l*1024*256;
    const ushort_t* ipl2= ipw_l + (size_t)l*1024*256;
    const ushort_t* xph = xpw_h + (size_t)l*64*512;
    const ushort_t* xpl = xpw_l + (size_t)l*64*512;
    const ushort_t* oph = opw_h + (size_t)l*256*512;
    const ushort_t* opl = opw_l + (size_t)l*256*512;
    float sz[32];
    const ushort_t* sAh = sFh + lm*264 + lq*8;
    const ushort_t* sAl = sFl + lm*264 + lq*8;

    // ---- Z pass: z = feat @ ipw[512:1024]^T ; wave's 64 cols in 2 slices ----
    __syncthreads();    // prior readers of C region done
    #pragma unroll
    for (int half = 0; half < 2; ++half) {
      f32x4 acc[2][2];
      #pragma unroll
      for (int mi = 0; mi < 2; ++mi)
        #pragma unroll
        for (int nt = 0; nt < 2; ++nt) acc[mi][nt] = (f32x4){0.f,0.f,0.f,0.f};
      int row0 = 512 + wave*64 + half*32;
      gemm2p<8, 264, 256>(sAh, sAl,
                          iph + (size_t)(row0+lm)*256 + lq*8,
                          ipl2 + (size_t)(row0+lm)*256 + lq*8, acc);
      int nb = wave*64 + half*32;
      #pragma unroll
      for (int mi = 0; mi < 2; ++mi)
        #pragma unroll
        for (int nt = 0; nt < 2; ++nt)
          #pragma unroll
          for (int r2 = 0; r2 < 4; ++r2)
            sZT[(mi*16 + lq*4 + r2)*524 + nb + nt*16 + lm] = acc[mi][nt][r2];
    }
    __syncthreads();
    #pragma unroll
    for (int t = 0; t < 32; ++t) sz[t] = silu_f(sZT[t*524 + d]);
    __syncthreads();

    // ---- U pass: u_pre = feat @ ipw[0:512]^T -> sZT (2 slices) ----
    #pragma unroll
    for (int half = 0; half < 2; ++half) {
      f32x4 acc[2][2];
      #pragma unroll
      for (int mi = 0; mi < 2; ++mi)
        #pragma unroll
        for (int nt = 0; nt < 2; ++nt) acc[mi][nt] = (f32x4){0.f,0.f,0.f,0.f};
      int row0 = wave*64 + half*32;
      gemm2p<8, 264, 256>(sAh, sAl,
                          iph + (size_t)(row0+lm)*256 + lq*8,
                          ipl2 + (size_t)(row0+lm)*256 + lq*8, acc);
      int nb = wave*64 + half*32;
      #pragma unroll
      for (int mi = 0; mi < 2; ++mi)
        #pragma unroll
        for (int nt = 0; nt < 2; ++nt)
          #pragma unroll
          for (int r2 = 0; r2 < 4; ++r2)
            sZT[(mi*16 + lq*4 + r2)*524 + nb + nt*16 + lm] = acc[mi][nt][r2];
    }
    __syncthreads();
    // depthwise conv (K=4, causal) + silu, per channel d; u -> packed LDS only
    {
      float xcol[32];
      #pragma unroll
      for (int t = 0; t < 32; ++t) xcol[t] = sZT[t*524 + d];
      __syncthreads();   // sZT dead; sUh/sUl may now be written
      const float* cwl = cw + (size_t)l*512*4 + (size_t)d*4;
      float w0 = cwl[0], w1c = cwl[1], w2c = cwl[2], w3 = cwl[3];
      float bias = cb[l*512 + d];
      float p1 = 0.f, p2 = 0.f, p3 = 0.f;
      #pragma unroll
      for (int t = 0; t < 32; ++t) {
        float a = bias + w0*p3 + w1c*p2 + w2c*p1 + w3*xcol[t];
        float uv = silu_f(a);
        ushort_t hh, ll; bf16_split(uv, hh, ll);
        sUh[t*520 + d] = hh;
        sUl[t*520 + d] = ll;
        p3 = p2; p2 = p1; p1 = xcol[t];
      }
    }
    __syncthreads();

    // ---- xproj: dbc = u @ xpw^T (48(->64) x 512), K split across wave halves ----
    {
      f32x4 acx[2] = {(f32x4){0.f,0.f,0.f,0.f}, (f32x4){0.f,0.f,0.f,0.f}};
      int wg = wave & 3, kh = wave >> 2;
      gemm1p<8, 520, 512>(sUh + lm*520 + kh*256 + lq*8,
                          sUl + lm*520 + kh*256 + lq*8,
                          xph + (size_t)(wg*16+lm)*512 + kh*256 + lq*8,
                          xpl + (size_t)(wg*16+lm)*512 + kh*256 + lq*8, acx);
      if (wave >= 4) {
        #pragma unroll
        for (int mi = 0; mi < 2; ++mi)
          #pragma unroll
          for (int r2 = 0; r2 < 4; ++r2)
            sDbc[(mi*16 + lq*4 + r2)*68 + wg*16 + lm] = acx[mi][r2];
      }
      __syncthreads();
      if (wave < 4) {
        #pragma unroll
        for (int mi = 0; mi < 2; ++mi)
          #pragma unroll
          for (int r2 = 0; r2 < 4; ++r2)
            sDbc[(mi*16 + lq*4 + r2)*68 + wg*16 + lm] += acx[mi][r2];
      }
      __syncthreads();
    }

    // ---- dtproj + selective scan + gate; y -> sUh/sUl in place ----
    {
      const float* dpwl = dpw + (size_t)l*512*16 + (size_t)d*16;
      f32x4 wv[4];
      #pragma unroll
      for (int k = 0; k < 4; ++k) wv[k] = *(const f32x4*)(dpwl + 4*k);
      const float* al2 = alog + (size_t)l*512*16 + (size_t)d*16;
      float cc[16], hh2[16];
      #pragma unroll
      for (int n = 0; n < 16; ++n) {
        cc[n] = -__expf(al2[n]) * 1.44269504f;
        hh2[n] = 0.f;
      }
      float bias = dpb[l*512 + d], dskv = dsk[l*512 + d];
      #pragma unroll
      for (int t = 0; t < 32; ++t) {
        const float* rowp = sDbc + t*68;
        float raw = bias;
        #pragma unroll
        for (int k = 0; k < 4; ++k) {
          f32x4 rd = *(const f32x4*)(rowp + 4*k);
          raw += wv[k][0]*rd[0] + wv[k][1]*rd[1] + wv[k][2]*rd[2] + wv[k][3]*rd[3];
        }
        float dtv = (raw > 20.f) ? raw : __logf(1.f + __expf(raw));
        int ui = t*520 + d;
        float uv = bf16_to_f(sUh[ui]) + bf16_to_f(sUl[ui]);
        float du = dtv * uv;
        float yv = 0.f;
        #pragma unroll
        for (int k = 0; k < 4; ++k) {
          f32x4 rb = *(const f32x4*)(rowp + 16 + 4*k);
          f32x4 rc = *(const f32x4*)(rowp + 32 + 4*k);
          #pragma unroll
          for (int j = 0; j < 4; ++j) {
            int n = 4*k + j;
            float en = exp2f(dtv * cc[n]);
            hh2[n] = en*hh2[n] + du*rb[j];
            yv += hh2[n]*rc[j];
          }
        }
        float yg = (yv + uv*dskv) * sz[t];
        ushort_t hh, ll; bf16_split(yg, hh, ll);
        sUh[ui] = hh;     // own-column in-place overwrite (u consumed this iter)
        sUl[ui] = ll;
      }
    }
    __syncthreads();

    // ---- out_proj (256 x 512) + residual + LN ----
    {
      f32x4 ao[2][2];
      #pragma unroll
      for (int mi = 0; mi < 2; ++mi)
        #pragma unroll
        for (int nt = 0; nt < 2; ++nt) ao[mi][nt] = (f32x4){0.f,0.f,0.f,0.f};
      int nb = wave*32;
      gemm2p<16, 520, 512>(sUh + lm*520 + lq*8, sUl + lm*520 + lq*8,
                           oph + (size_t)(nb+lm)*512 + lq*8,
                           opl + (size_t)(nb+lm)*512 + lq*8, ao);
      __syncthreads();   // all waves done reading sUh/sUl; sDbc readers done too
      #pragma unroll
      for (int mi = 0; mi < 2; ++mi)
        #pragma unroll
        for (int nt = 0; nt < 2; ++nt)
          #pragma unroll
          for (int r2 = 0; r2 < 4; ++r2)
            sT2[(mi*16 + lq*4 + r2)*260 + nb + nt*16 + lm] = ao[mi][nt][r2];
    }
    __syncthreads();
    ln_block(sT2, sF32, nullptr, lng, lnb, sF32, sFh, sFl, tid);
    __syncthreads();
  }

  // ================= classifier (token 31) =================
  {
    int o = tid >> 2, q = tid & 3;
    const float* fr = sF32 + 31*260;
    const float* wr = w1 + (size_t)o*256 + q*64;
    float s = 0.f;
    #pragma unroll 16
    for (int k = 0; k < 64; ++k) s += wr[k]*fr[q*64 + k];
    s += __shfl_xor(s, 1); s += __shfl_xor(s, 2);
    if (q == 0) sHid[o] = fmaxf(s + b1[o], 0.f);
    __syncthreads();
    if (tid < 2) {
      float oo = b2[tid];
      #pragma unroll 8
      for (int k = 0; k < 128; ++k) oo += w2[tid*128 + k]*sHid[k];
      out[b*2 + tid] = oo;
    }
  }
}

// ---------------- launch ----------------
extern "C" void kernel_launch(void* const* d_in, const int* in_sizes, int n_in,
                              void* d_out, int out_size, void* d_ws, size_t ws_size,
                              hipStream_t stream) {
  const float* x    = (const float*)d_in[0];
  const float* ep   = (const float*)d_in[1];
  const float* ef   = (const float*)d_in[2];
  const float* ed   = (const float*)d_in[3];
  const float* plw  = (const float*)d_in[4];
  const float* plb  = (const float*)d_in[5];
  const float* piw  = (const float*)d_in[6];
  const float* pib  = (const float*)d_in[7];
  const float* fw   = (const float*)d_in[8];
  const float* fb   = (const float*)d_in[9];
  const float* tng  = (const float*)d_in[10];
  const float* tnb  = (const float*)d_in[11];
  const float* ipw  = (const float*)d_in[12];
  const float* cw   = (const float*)d_in[13];
  const float* cb   = (const float*)d_in[14];
  const float* xpw  = (const float*)d_in[15];
  const float* dpw  = (const float*)d_in[16];
  const float* dpb  = (const float*)d_in[17];
  const float* alog = (const float*)d_in[18];
  const float* dsk  = (const float*)d_in[19];
  const float* opw  = (const float*)d_in[20];
  const float* lng  = (const float*)d_in[21];
  const float* lnb  = (const float*)d_in[22];
  const float* w1   = (const float*)d_in[23];
  const float* b1   = (const float*)d_in[24];
  const float* w2   = (const float*)d_in[25];
  const float* b2   = (const float*)d_in[26];

  // workspace: split-bf16 weights only
  ushort_t* ipw_h = (ushort_t*)d_ws;
  ushort_t* ipw_l = ipw_h + (size_t)NIP;
  ushort_t* opw_h = ipw_l + (size_t)NIP;
  ushort_t* opw_l = opw_h + (size_t)NOP;
  ushort_t* xpw_h = opw_l + (size_t)NOP;
  ushort_t* xpw_l = xpw_h + (size_t)NXP;
  ushort_t* fw_h  = xpw_l + (size_t)NXP;
  ushort_t* fw_l  = fw_h  + (size_t)NFW;

  static int smem_set = 0;
  if (!smem_set) {
    hipFuncSetAttribute(reinterpret_cast<const void*>(mega_kernel),
                        hipFuncAttributeMaxDynamicSharedMemorySize, SMEM_TOTAL);
    smem_set = 1;
  }

  prep_w<<<NPREP/256, 256, 0, stream>>>(ipw, opw, xpw, fw,
      ipw_h, ipw_l, opw_h, opw_l, xpw_h, xpw_l, fw_h, fw_l);

  mega_kernel<<<BATCH, 512, SMEM_TOTAL, stream>>>(
      x, ep, ef, ed, plw, plb, piw, pib,
      fw_h, fw_l, fb, tng, tnb,
      ipw_h, ipw_l, cw, cb, xpw_h, xpw_l,
      dpw, dpb, alog, dsk, opw_h, opw_l,
      lng, lnb, w1, b1, w2, b2, (float*)d_out);
}

// Round 12
// 440.066 us; speedup vs baseline: 1.3832x; 1.0355x over previous
//
#include <hip/hip_runtime.h>
#include <math.h>

// BlockwiseEarlyExitMamba: B=128, L=64, EXIT_POS=32 -> only t<32 matter.
// v13: v12 structure (512-thread per-batch mega-kernel, 359us) with the
// instruction-count attack: SINGLE-bf16 activations (weights stay hi/lo).
// mfma3 -> mfma2 (-33% MFMA), activation LDS traffic halved, bf16
// split/reconstruct VALU halved. Scan/conv/LN internal math stays f32.
#define BATCH 128

using bf16x8 = __attribute__((ext_vector_type(8))) short;
using f32x4  = __attribute__((ext_vector_type(4))) float;
typedef unsigned short ushort_t;
typedef unsigned int   uint_t;

__device__ __forceinline__ float silu_f(float x) { return x / (1.f + __expf(-x)); }

__device__ __forceinline__ ushort_t bf16_rne(float f) {
  unsigned int u = __float_as_uint(f);
  u += 0x7FFFu + ((u >> 16) & 1u);
  return (ushort_t)(u >> 16);
}
__device__ __forceinline__ float bf16_to_f(ushort_t h) {
  return __uint_as_float(((unsigned int)h) << 16);
}
__device__ __forceinline__ void bf16_split(float f, ushort_t& hi, ushort_t& lo) {
  hi = bf16_rne(f);
  lo = bf16_rne(f - bf16_to_f(hi));
}

// single-A x split-W: a*(wh+wl) = a*wh + a*wl  (2 MFMAs)
__device__ __forceinline__ f32x4 mfma2(bf16x8 a, bf16x8 wh, bf16x8 wl, f32x4 acc) {
  acc = __builtin_amdgcn_mfma_f32_16x16x32_bf16(a, wh, acc, 0, 0, 0);
  acc = __builtin_amdgcn_mfma_f32_16x16x32_bf16(a, wl, acc, 0, 0, 0);
  return acc;
}

// 2-tile (32 out cols) GEMM slice, 1-deep prefetch. A single bf16 (LDS),
// W hi/lo (global). sA pre-offset: + lm*AP + lq*8. wh/wl: + (row0+lm)*WP + lq*8.
template<int KSTEPS, int AP, int WP>
__device__ __forceinline__ void gemm2p(
    const ushort_t* sA,
    const ushort_t* wh, const ushort_t* wl,
    f32x4 acc[2][2]) {
  bf16x8 ca0  = *(const bf16x8*)(sA);
  bf16x8 ca1  = *(const bf16x8*)(sA + 16*AP);
  bf16x8 cw0  = *(const bf16x8*)(wh);
  bf16x8 cwl0 = *(const bf16x8*)(wl);
  bf16x8 cw1  = *(const bf16x8*)(wh + 16*WP);
  bf16x8 cwl1 = *(const bf16x8*)(wl + 16*WP);
  #pragma unroll
  for (int ks = 0; ks < KSTEPS; ++ks) {
    bf16x8 na0=ca0, na1=ca1;
    bf16x8 nw0=cw0, nwl0=cwl0, nw1=cw1, nwl1=cwl1;
    if (ks + 1 < KSTEPS) {
      int kn = (ks+1)*32;
      na0  = *(const bf16x8*)(sA + kn);
      na1  = *(const bf16x8*)(sA + 16*AP + kn);
      nw0  = *(const bf16x8*)(wh + kn);
      nwl0 = *(const bf16x8*)(wl + kn);
      nw1  = *(const bf16x8*)(wh + 16*WP + kn);
      nwl1 = *(const bf16x8*)(wl + 16*WP + kn);
    }
    acc[0][0] = mfma2(ca0, cw0, cwl0, acc[0][0]);
    acc[1][0] = mfma2(ca1, cw0, cwl0, acc[1][0]);
    acc[0][1] = mfma2(ca0, cw1, cwl1, acc[0][1]);
    acc[1][1] = mfma2(ca1, cw1, cwl1, acc[1][1]);
    ca0=na0; ca1=na1;
    cw0=nw0; cwl0=nwl0; cw1=nw1; cwl1=nwl1;
  }
}

// 1-tile (16 out cols) variant for xproj.
template<int KSTEPS, int AP, int WP>
__device__ __forceinline__ void gemm1p(
    const ushort_t* sA,
    const ushort_t* wh, const ushort_t* wl,
    f32x4 acc[2]) {
  bf16x8 ca0  = *(const bf16x8*)(sA);
  bf16x8 ca1  = *(const bf16x8*)(sA + 16*AP);
  bf16x8 cw0  = *(const bf16x8*)(wh);
  bf16x8 cwl0 = *(const bf16x8*)(wl);
  #pragma unroll
  for (int ks = 0; ks < KSTEPS; ++ks) {
    bf16x8 na0=ca0, na1=ca1;
    bf16x8 nw0=cw0, nwl0=cwl0;
    if (ks + 1 < KSTEPS) {
      int kn = (ks+1)*32;
      na0  = *(const bf16x8*)(sA + kn);
      na1  = *(const bf16x8*)(sA + 16*AP + kn);
      nw0  = *(const bf16x8*)(wh + kn);
      nwl0 = *(const bf16x8*)(wl + kn);
    }
    acc[0] = mfma2(ca0, cw0, cwl0, acc[0]);
    acc[1] = mfma2(ca1, cw0, cwl0, acc[1]);
    ca0=na0; ca1=na1;
    cw0=nw0; cwl0=nwl0;
  }
}

// ---------------- merged weight prep: fp32 -> hi/lo bf16 ----------------
#define NIP (4*1024*256)     // in_proj
#define NOP (4*256*512)      // out_proj
#define NXP (4*64*512)       // xproj padded 48->64 rows
#define NFW (256*160)        // fusion_w padded 136->160 cols
#define NPREP (NIP+NOP+NXP+NFW)   // 1744896 = 6816*256
__global__ __launch_bounds__(256) void prep_w(
    const float* __restrict__ ipw, const float* __restrict__ opw,
    const float* __restrict__ xpw, const float* __restrict__ fw,
    ushort_t* __restrict__ ih, ushort_t* __restrict__ il,
    ushort_t* __restrict__ oh, ushort_t* __restrict__ ol,
    ushort_t* __restrict__ xh, ushort_t* __restrict__ xl,
    ushort_t* __restrict__ fh, ushort_t* __restrict__ fl) {
  int i = blockIdx.x*256 + threadIdx.x;
  float v; ushort_t h, l;
  if (i < NIP) {
    v = ipw[i]; bf16_split(v, h, l); ih[i] = h; il[i] = l;
  } else if (i < NIP+NOP) {
    int j = i - NIP;
    v = opw[j]; bf16_split(v, h, l); oh[j] = h; ol[j] = l;
  } else if (i < NIP+NOP+NXP) {
    int j = i - (NIP+NOP);
    int lay = j >> 15;            // 64*512 = 32768
    int r = (j >> 9) & 63, c = j & 511;
    v = (r < 48) ? xpw[(size_t)lay*48*512 + r*512 + c] : 0.f;
    bf16_split(v, h, l); xh[j] = h; xl[j] = l;
  } else {
    int j = i - (NIP+NOP+NXP);
    int r = j / 160, c = j - r*160;
    v = (c < 136) ? fw[r*136 + c] : 0.f;
    bf16_split(v, h, l); fh[j] = h; fl[j] = l;
  }
}

// ---------------- LDS layout (bytes) ----------------
// A: sF32 f32 [32][260]                 33280  (residual feat, persistent)
// B: sT2 f32 [32][260]                  33280  (aliased: sFh us [32][264],
//                                               sDbc f32 [32][68], sHid f32[128])
// C: sZT f32 [32][524]                  67072  (aliased: sUh us [32][520],
//                                               catH us [32][168])
#define OFF_A 0
#define OFF_B 33280
#define OFF_C 66560
#define SMEM_TOTAL 133632

// LN of a [32][256] tile in LDS; 16 threads/row. Reads sIn (+resid +addv),
// internal barrier, writes sF32o + single bf16.
__device__ __forceinline__ void ln_block(
    const float* sIn, const float* resid, const float* addv,
    const float* __restrict__ g, const float* __restrict__ bb,
    float* sF32o, ushort_t* sFho, int tid) {
  int row = tid >> 4, sub = tid & 15;
  float v[16];
  float s = 0.f;
  #pragma unroll
  for (int i = 0; i < 16; ++i) {
    int c = sub + 16*i;
    float t = sIn[row*260 + c];
    if (resid) t += resid[row*260 + c];
    if (addv)  t += addv[c];
    v[i] = t; s += t;
  }
  s += __shfl_xor(s, 1); s += __shfl_xor(s, 2); s += __shfl_xor(s, 4); s += __shfl_xor(s, 8);
  float mu = s * (1.f/256.f);
  float s2 = 0.f;
  #pragma unroll
  for (int i = 0; i < 16; ++i) { float dv = v[i]-mu; s2 += dv*dv; }
  s2 += __shfl_xor(s2, 1); s2 += __shfl_xor(s2, 2); s2 += __shfl_xor(s2, 4); s2 += __shfl_xor(s2, 8);
  float rs = rsqrtf(s2*(1.f/256.f) + 1e-5f);
  __syncthreads();              // sIn aliases sFho: read-before, write-after
  #pragma unroll
  for (int i = 0; i < 16; ++i) {
    int c = sub + 16*i;
    float o = (v[i]-mu)*rs*g[c] + bb[c];
    sF32o[row*260 + c] = o;
    sFho[row*264 + c] = bf16_rne(o);
  }
}

// ---------------- the mega kernel: tokenizer + 4 layers + classifier ----------
__global__ __launch_bounds__(512, 2) void mega_kernel(
    const float* __restrict__ x,
    const float* __restrict__ ep, const float* __restrict__ ef, const float* __restrict__ ed,
    const float* __restrict__ plw, const float* __restrict__ plb,
    const float* __restrict__ piw, const float* __restrict__ pib,
    const ushort_t* __restrict__ fw_h, const ushort_t* __restrict__ fw_l,
    const float* __restrict__ fb,
    const float* __restrict__ tng, const float* __restrict__ tnb,
    const ushort_t* __restrict__ ipw_h, const ushort_t* __restrict__ ipw_l,
    const float* __restrict__ cw, const float* __restrict__ cb,
    const ushort_t* __restrict__ xpw_h, const ushort_t* __restrict__ xpw_l,
    const float* __restrict__ dpw, const float* __restrict__ dpb,
    const float* __restrict__ alog, const float* __restrict__ dsk,
    const ushort_t* __restrict__ opw_h, const ushort_t* __restrict__ opw_l,
    const float* __restrict__ lng, const float* __restrict__ lnb,
    const float* __restrict__ w1, const float* __restrict__ b1,
    const float* __restrict__ w2, const float* __restrict__ b2,
    float* __restrict__ out) {
  extern __shared__ __align__(16) char sm[];
  float*    sF32 = (float*)(sm + OFF_A);       // [32][260]
  float*    sT2  = (float*)(sm + OFF_B);       // [32][260] GEMM frag dump
  ushort_t* sFh  = (ushort_t*)(sm + OFF_B);    // [32][264] feat bf16
  float*    sDbc = (float*)(sm + OFF_B);       // [32][68]
  float*    sHid = (float*)(sm + OFF_B);       // [128]
  float*    sZT  = (float*)(sm + OFF_C);       // [32][524] f32 staging
  ushort_t* sUh  = (ushort_t*)(sm + OFF_C);    // [32][520] u -> y (bf16)
  ushort_t* catH = (ushort_t*)(sm + OFF_C);    // [32][168]

  const int tid  = threadIdx.x;
  const int b    = blockIdx.x;
  const int wave = tid >> 6, lane = tid & 63;
  const int lm   = lane & 15, lq = lane >> 4;
  const int d    = tid;                        // channel owned by this thread (0..511)

  // ================= tokenizer =================
  {
    int r = tid >> 4, cl = tid & 15;
    const float* xr = x + ((size_t)b*64 + r)*5;   // L=64 stride in input
    float x0 = xr[0], x1 = xr[1], x2 = xr[2], x3 = xr[3], x4 = xr[4];
    int proto = min(max((int)x0, 0), 255);
    int flags = min(max((int)x2, 0), 63);
    int direc = min(max((int)x4, 0), 1);
    #pragma unroll
    for (int j = 0; j < 10; ++j) {
      int c = cl + 16*j;
      float v;
      if (c < 32)       v = ep[proto*32 + c];
      else if (c < 64)  v = x1*plw[c-32] + plb[c-32];
      else if (c < 96)  v = ef[flags*32 + (c-64)];
      else if (c < 128) v = x3*piw[c-96] + pib[c-96];
      else if (c < 136) v = ed[direc*8 + (c-128)];
      else              v = 0.f;
      catH[r*168 + c] = bf16_rne(v);
    }
  }
  __syncthreads();
  // pre = cat @ fw^T (M=32, N=256, K=160); dump to sT2 (B region, free)
  {
    f32x4 acc[2][2];
    #pragma unroll
    for (int mi = 0; mi < 2; ++mi)
      #pragma unroll
      for (int nt = 0; nt < 2; ++nt) acc[mi][nt] = (f32x4){0.f,0.f,0.f,0.f};
    int nb = wave*32;
    gemm2p<5, 168, 160>(catH + lm*168 + lq*8,
                        fw_h + (size_t)(nb+lm)*160 + lq*8,
                        fw_l + (size_t)(nb+lm)*160 + lq*8, acc);
    #pragma unroll
    for (int mi = 0; mi < 2; ++mi)
      #pragma unroll
      for (int nt = 0; nt < 2; ++nt)
        #pragma unroll
        for (int r2 = 0; r2 < 4; ++r2)
          sT2[(mi*16 + lq*4 + r2)*260 + nb + nt*16 + lm] = acc[mi][nt][r2];
  }
  __syncthreads();
  ln_block(sT2, nullptr, fb, tng, tnb, sF32, sFh, tid);
  __syncthreads();

  // ================= 4 mamba layers =================
  #pragma unroll 1
  for (int l = 0; l < 4; ++l) {
    const ushort_t* iph = ipw_h + (size_t)l*1024*256;
    const ushort_t* ipl2= ipw_l + (size_t)l*1024*256;
    const ushort_t* xph = xpw_h + (size_t)l*64*512;
    const ushort_t* xpl = xpw_l + (size_t)l*64*512;
    const ushort_t* oph = opw_h + (size_t)l*256*512;
    const ushort_t* opl = opw_l + (size_t)l*256*512;
    float sz[32];
    const ushort_t* sA = sFh + lm*264 + lq*8;

    // ---- Z pass: z = feat @ ipw[512:1024]^T ; wave's 64 cols in 2 slices ----
    __syncthreads();    // prior readers of C region done
    #pragma unroll
    for (int half = 0; half < 2; ++half) {
      f32x4 acc[2][2];
      #pragma unroll
      for (int mi = 0; mi < 2; ++mi)
        #pragma unroll
        for (int nt = 0; nt < 2; ++nt) acc[mi][nt] = (f32x4){0.f,0.f,0.f,0.f};
      int row0 = 512 + wave*64 + half*32;
      gemm2p<8, 264, 256>(sA,
                          iph + (size_t)(row0+lm)*256 + lq*8,
                          ipl2 + (size_t)(row0+lm)*256 + lq*8, acc);
      int nb = wave*64 + half*32;
      #pragma unroll
      for (int mi = 0; mi < 2; ++mi)
        #pragma unroll
        for (int nt = 0; nt < 2; ++nt)
          #pragma unroll
          for (int r2 = 0; r2 < 4; ++r2)
            sZT[(mi*16 + lq*4 + r2)*524 + nb + nt*16 + lm] = acc[mi][nt][r2];
    }
    __syncthreads();
    #pragma unroll
    for (int t = 0; t < 32; ++t) sz[t] = silu_f(sZT[t*524 + d]);
    __syncthreads();

    // ---- U pass: u_pre = feat @ ipw[0:512]^T -> sZT (2 slices) ----
    #pragma unroll
    for (int half = 0; half < 2; ++half) {
      f32x4 acc[2][2];
      #pragma unroll
      for (int mi = 0; mi < 2; ++mi)
        #pragma unroll
        for (int nt = 0; nt < 2; ++nt) acc[mi][nt] = (f32x4){0.f,0.f,0.f,0.f};
      int row0 = wave*64 + half*32;
      gemm2p<8, 264, 256>(sA,
                          iph + (size_t)(row0+lm)*256 + lq*8,
                          ipl2 + (size_t)(row0+lm)*256 + lq*8, acc);
      int nb = wave*64 + half*32;
      #pragma unroll
      for (int mi = 0; mi < 2; ++mi)
        #pragma unroll
        for (int nt = 0; nt < 2; ++nt)
          #pragma unroll
          for (int r2 = 0; r2 < 4; ++r2)
            sZT[(mi*16 + lq*4 + r2)*524 + nb + nt*16 + lm] = acc[mi][nt][r2];
    }
    __syncthreads();
    // depthwise conv (K=4, causal) + silu, per channel d; u -> bf16 LDS
    {
      float xcol[32];
      #pragma unroll
      for (int t = 0; t < 32; ++t) xcol[t] = sZT[t*524 + d];
      __syncthreads();   // sZT dead; sUh may now be written
      const float* cwl = cw + (size_t)l*512*4 + (size_t)d*4;
      float w0 = cwl[0], w1c = cwl[1], w2c = cwl[2], w3 = cwl[3];
      float bias = cb[l*512 + d];
      float p1 = 0.f, p2 = 0.f, p3 = 0.f;
      #pragma unroll
      for (int t = 0; t < 32; ++t) {
        float a = bias + w0*p3 + w1c*p2 + w2c*p1 + w3*xcol[t];
        sUh[t*520 + d] = bf16_rne(silu_f(a));
        p3 = p2; p2 = p1; p1 = xcol[t];
      }
    }
    __syncthreads();

    // ---- xproj: dbc = u @ xpw^T (48(->64) x 512), K split across wave halves ----
    {
      f32x4 acx[2] = {(f32x4){0.f,0.f,0.f,0.f}, (f32x4){0.f,0.f,0.f,0.f}};
      int wg = wave & 3, kh = wave >> 2;
      gemm1p<8, 520, 512>(sUh + lm*520 + kh*256 + lq*8,
                          xph + (size_t)(wg*16+lm)*512 + kh*256 + lq*8,
                          xpl + (size_t)(wg*16+lm)*512 + kh*256 + lq*8, acx);
      if (wave >= 4) {
        #pragma unroll
        for (int mi = 0; mi < 2; ++mi)
          #pragma unroll
          for (int r2 = 0; r2 < 4; ++r2)
            sDbc[(mi*16 + lq*4 + r2)*68 + wg*16 + lm] = acx[mi][r2];
      }
      __syncthreads();
      if (wave < 4) {
        #pragma unroll
        for (int mi = 0; mi < 2; ++mi)
          #pragma unroll
          for (int r2 = 0; r2 < 4; ++r2)
            sDbc[(mi*16 + lq*4 + r2)*68 + wg*16 + lm] += acx[mi][r2];
      }
      __syncthreads();
    }

    // ---- dtproj + selective scan + gate; y -> sUh in place ----
    {
      const float* dpwl = dpw + (size_t)l*512*16 + (size_t)d*16;
      f32x4 wv[4];
      #pragma unroll
      for (int k = 0; k < 4; ++k) wv[k] = *(const f32x4*)(dpwl + 4*k);
      const float* al2 = alog + (size_t)l*512*16 + (size_t)d*16;
      float cc[16], hh2[16];
      #pragma unroll
      for (int n = 0; n < 16; ++n) {
        cc[n] = -__expf(al2[n]) * 1.44269504f;
        hh2[n] = 0.f;
      }
      float bias = dpb[l*512 + d], dskv = dsk[l*512 + d];
      #pragma unroll
      for (int t = 0; t < 32; ++t) {
        const float* rowp = sDbc + t*68;
        float raw = bias;
        #pragma unroll
        for (int k = 0; k < 4; ++k) {
          f32x4 rd = *(const f32x4*)(rowp + 4*k);
          raw += wv[k][0]*rd[0] + wv[k][1]*rd[1] + wv[k][2]*rd[2] + wv[k][3]*rd[3];
        }
        float dtv = (raw > 20.f) ? raw : __logf(1.f + __expf(raw));
        int ui = t*520 + d;
        float uv = bf16_to_f(sUh[ui]);
        float du = dtv * uv;
        float yv = 0.f;
        #pragma unroll
        for (int k = 0; k < 4; ++k) {
          f32x4 rb = *(const f32x4*)(rowp + 16 + 4*k);
          f32x4 rc = *(const f32x4*)(rowp + 32 + 4*k);
          #pragma unroll
          for (int j = 0; j < 4; ++j) {
            int n = 4*k + j;
            float en = exp2f(dtv * cc[n]);
            hh2[n] = en*hh2[n] + du*rb[j];
            yv += hh2[n]*rc[j];
          }
        }
        float yg = (yv + uv*dskv) * sz[t];
        sUh[ui] = bf16_rne(yg);   // own-column in-place overwrite
      }
    }
    __syncthreads();

    // ---- out_proj (256 x 512) + residual + LN ----
    {
      f32x4 ao[2][2];
      #pragma unroll
      for (int mi = 0; mi < 2; ++mi)
        #pragma unroll
        for (int nt = 0; nt < 2; ++nt) ao[mi][nt] = (f32x4){0.f,0.f,0.f,0.f};
      int nb = wave*32;
      gemm2p<16, 520, 512>(sUh + lm*520 + lq*8,
                           oph + (size_t)(nb+lm)*512 + lq*8,
                           opl + (size_t)(nb+lm)*512 + lq*8, ao);
      __syncthreads();   // all waves done reading sUh; sDbc readers done too
      #pragma unroll
      for (int mi = 0; mi < 2; ++mi)
        #pragma unroll
        for (int nt = 0; nt < 2; ++nt)
          #pragma unroll
          for (int r2 = 0; r2 < 4; ++r2)
            sT2[(mi*16 + lq*4 + r2)*260 + nb + nt*16 + lm] = ao[mi][nt][r2];
    }
    __syncthreads();
    ln_block(sT2, sF32, nullptr, lng, lnb, sF32, sFh, tid);
    __syncthreads();
  }

  // ================= classifier (token 31) =================
  {
    int o = tid >> 2, q = tid & 3;
    const float* fr = sF32 + 31*260;
    const float* wr = w1 + (size_t)o*256 + q*64;
    float s = 0.f;
    #pragma unroll 16
    for (int k = 0; k < 64; ++k) s += wr[k]*fr[q*64 + k];
    s += __shfl_xor(s, 1); s += __shfl_xor(s, 2);
    if (q == 0) sHid[o] = fmaxf(s + b1[o], 0.f);
    __syncthreads();
    if (tid < 2) {
      float oo = b2[tid];
      #pragma unroll 8
      for (int k = 0; k < 128; ++k) oo += w2[tid*128 + k]*sHid[k];
      out[b*2 + tid] = oo;
    }
  }
}

// ---------------- launch ----------------
extern "C" void kernel_launch(void* const* d_in, const int* in_sizes, int n_in,
                              void* d_out, int out_size, void* d_ws, size_t ws_size,
                              hipStream_t stream) {
  const float* x    = (const float*)d_in[0];
  const float* ep   = (const float*)d_in[1];
  const float* ef   = (const float*)d_in[2];
  const float* ed   = (const float*)d_in[3];
  const float* plw  = (const float*)d_in[4];
  const float* plb  = (const float*)d_in[5];
  const float* piw  = (const float*)d_in[6];
  const float* pib  = (const float*)d_in[7];
  const float* fw   = (const float*)d_in[8];
  const float* fb   = (const float*)d_in[9];
  const float* tng  = (const float*)d_in[10];
  const float* tnb  = (const float*)d_in[11];
  const float* ipw  = (const float*)d_in[12];
  const float* cw   = (const float*)d_in[13];
  const float* cb   = (const float*)d_in[14];
  const float* xpw  = (const float*)d_in[15];
  const float* dpw  = (const float*)d_in[16];
  const float* dpb  = (const float*)d_in[17];
  const float* alog = (const float*)d_in[18];
  const float* dsk  = (const float*)d_in[19];
  const float* opw  = (const float*)d_in[20];
  const float* lng  = (const float*)d_in[21];
  const float* lnb  = (const float*)d_in[22];
  const float* w1   = (const float*)d_in[23];
  const float* b1   = (const float*)d_in[24];
  const float* w2   = (const float*)d_in[25];
  const float* b2   = (const float*)d_in[26];

  // workspace: split-bf16 weights only
  ushort_t* ipw_h = (ushort_t*)d_ws;
  ushort_t* ipw_l = ipw_h + (size_t)NIP;
  ushort_t* opw_h = ipw_l + (size_t)NIP;
  ushort_t* opw_l = opw_h + (size_t)NOP;
  ushort_t* xpw_h = opw_l + (size_t)NOP;
  ushort_t* xpw_l = xpw_h + (size_t)NXP;
  ushort_t* fw_h  = xpw_l + (size_t)NXP;
  ushort_t* fw_l  = fw_h  + (size_t)NFW;

  static int smem_set = 0;
  if (!smem_set) {
    hipFuncSetAttribute(reinterpret_cast<const void*>(mega_kernel),
                        hipFuncAttributeMaxDynamicSharedMemorySize, SMEM_TOTAL);
    smem_set = 1;
  }

  prep_w<<<NPREP/256, 256, 0, stream>>>(ipw, opw, xpw, fw,
      ipw_h, ipw_l, opw_h, opw_l, xpw_h, xpw_l, fw_h, fw_l);

  mega_kernel<<<BATCH, 512, SMEM_TOTAL, stream>>>(
      x, ep, ef, ed, plw, plb, piw, pib,
      fw_h, fw_l, fb, tng, tnb,
      ipw_h, ipw_l, cw, cb, xpw_h, xpw_l,
      dpw, dpb, alog, dsk, opw_h, opw_l,
      lng, lnb, w1, b1, w2, b2, (float*)d_out);
}